// Round 5
// baseline (444.084 us; speedup 1.0000x reference)
//
#include <hip/hip_runtime.h>
#include <stdint.h>

// Problem constants
#define BB 2
#define SS 2048
#define HID 2048
#define NH 16
#define DD 128
#define NKV 4

typedef unsigned short u16;
typedef __attribute__((ext_vector_type(8))) short short8;   // 8 x bf16 (4 VGPRs) MFMA A/B frag
typedef __attribute__((ext_vector_type(4))) float f32x4;    // MFMA C/D frag

#if __has_builtin(__builtin_amdgcn_exp2f)
#define EXP2(x) __builtin_amdgcn_exp2f(x)
#else
#define EXP2(x) exp2f(x)
#endif

__device__ __forceinline__ u16 f2bf(float x) {
    union { float f; unsigned u; } v; v.f = x;
    unsigned u = v.u;
    return (u16)((u + 0x7FFFu + ((u >> 16) & 1u)) >> 16);   // RNE
}

// pack two fp32 -> bf16 pair by truncation (1 v_perm). lo in low 16, hi in high 16.
__device__ __forceinline__ unsigned pkbf(float lo, float hi) {
    return __builtin_amdgcn_perm(__float_as_uint(hi), __float_as_uint(lo), 0x07060302u);
}

// ---------------- prep: weight transposes only (activations convert fused into GEMM) --------
__global__ __launch_bounds__(256) void k_prep(const float* __restrict__ Wq,
                                              const float* __restrict__ Wk,
                                              const float* __restrict__ Wv,
                                              const float* __restrict__ Wo,
                                              u16* __restrict__ Wt,
                                              u16* __restrict__ Wot) {
    __shared__ float tile[32][33];
    const int v_ = blockIdx.x;           // 0..10239
    const int ty = v_ / 160;             // k-tile 0..63
    const int xt = v_ - ty * 160;        // n-tile 0..159
    const float* src; u16* dst; int N, n0;
    if (xt < 64)      { src = Wq; dst = Wt;                          N = 2048; n0 = xt * 32; }
    else if (xt < 80) { src = Wk; dst = Wt + (size_t)2048 * 2048;    N = 512;  n0 = (xt - 64) * 32; }
    else if (xt < 96) { src = Wv; dst = Wt + (size_t)2560 * 2048;    N = 512;  n0 = (xt - 80) * 32; }
    else              { src = Wo; dst = Wot;                         N = 2048; n0 = (xt - 96) * 32; }
    const int k0 = ty * 32;
    const int c = threadIdx.x & 31, r = threadIdx.x >> 5;
#pragma unroll
    for (int i = 0; i < 32; i += 8)
        tile[r + i][c] = src[(size_t)(k0 + r + i) * N + n0 + c];
    __syncthreads();
#pragma unroll
    for (int i = 0; i < 32; i += 8)
        dst[(size_t)(n0 + r + i) * 2048 + k0 + c] = f2bf(tile[c][r + i]);
}

// ---------------- fused QKV projection GEMM (pipelined K-loop, fp32 A staged+converted) ------
// grid (24, 32). bn<16: Q-proj (RoPE+scale -> qro); bn 16..19: K-proj (RoPE -> kro);
// bn 20..23: V-proj (-> vtr transposed).
// K-loop: register-staged global loads for tile i+1 issued before compute on tile i (LDS
// double buffer, one barrier/iter) -> loads overlap MFMA instead of stalling at vmcnt(0).
__global__ __launch_bounds__(256) void k_gemm_qkv(const float* __restrict__ qf32,
                                                  const float* __restrict__ kf32,
                                                  const float* __restrict__ vf32,
                                                  const u16* __restrict__ Wt,   // [3072][2048] bf16
                                                  const float* __restrict__ bq,
                                                  const float* __restrict__ bk,
                                                  const float* __restrict__ bv,
                                                  const float* __restrict__ fc,
                                                  const float* __restrict__ fs,
                                                  u16* __restrict__ qro,
                                                  u16* __restrict__ kro,
                                                  u16* __restrict__ vtr) {
    __shared__ char smem[32768];
    u16* As = (u16*)smem;                  // 2 bufs x 128x32 bf16 (16 KB)
    u16* Bs = (u16*)(smem + 16384);        // 2 bufs x 128x32 bf16 (16 KB)
    float* Ep = (float*)smem;              // epilogue scratch, aliased (post-loop only)

    const int tid = threadIdx.x;
    const int lane = tid & 63, wave = tid >> 6;
    const int bn = blockIdx.x;
    const int bm = blockIdx.y * 128;
    const float* A = (bn < 16) ? qf32 : (bn < 20) ? kf32 : vf32;

    const int srow = tid >> 2, spos = tid & 3;
    const int swz = (srow >> 1) & 3;
    const int c0 = (spos ^ swz) * 8;                 // swizzled global chunk (same for row+64)
    const float* gA0 = A + (size_t)(bm + srow) * 2048 + c0;
    const float* gA1 = gA0 + (size_t)64 * 2048;
    const u16* gB0 = Wt + (size_t)(bn * 128 + srow) * 2048 + c0;
    const u16* gB1 = gB0 + (size_t)64 * 2048;
    const int wo0 = srow * 32 + spos * 8;            // LDS dest (u16 units), linear per-thread
    const int wo1 = wo0 + 64 * 32;

    const int r = lane & 15, q4 = lane >> 4;
    const int wm = (wave & 1) * 64, wn = (wave >> 1) * 64;

    int aoff[4], boff[4];
#pragma unroll
    for (int i = 0; i < 4; i++) {
        const int ar = wm + i * 16 + r;
        aoff[i] = ar * 32 + ((q4 ^ ((ar >> 1) & 3)) << 3);
        const int br = wn + i * 16 + r;
        boff[i] = br * 32 + ((q4 ^ ((br >> 1) & 3)) << 3);
    }

    f32x4 acc[4][4] = {};

    // prologue: tile 0 -> buf 0
    {
        float4 a00 = *(const float4*)(gA0), a01 = *(const float4*)(gA0 + 4);
        float4 a10 = *(const float4*)(gA1), a11 = *(const float4*)(gA1 + 4);
        uint4 b0 = *(const uint4*)(gB0), b1 = *(const uint4*)(gB1);
        uint4 pa0 = make_uint4(pkbf(a00.x, a00.y), pkbf(a00.z, a00.w), pkbf(a01.x, a01.y), pkbf(a01.z, a01.w));
        uint4 pa1 = make_uint4(pkbf(a10.x, a10.y), pkbf(a10.z, a10.w), pkbf(a11.x, a11.y), pkbf(a11.z, a11.w));
        *(uint4*)(As + wo0) = pa0;
        *(uint4*)(As + wo1) = pa1;
        *(uint4*)(Bs + wo0) = b0;
        *(uint4*)(Bs + wo1) = b1;
    }
    __syncthreads();

    for (int i = 0; i < 64; i++) {
        const int par = i & 1;
        float4 a00, a01, a10, a11; uint4 b0, b1;
        if (i < 63) {                               // issue next-tile loads (in flight thru compute)
            gA0 += 32; gA1 += 32; gB0 += 32; gB1 += 32;
            a00 = *(const float4*)(gA0); a01 = *(const float4*)(gA0 + 4);
            a10 = *(const float4*)(gA1); a11 = *(const float4*)(gA1 + 4);
            b0 = *(const uint4*)(gB0);   b1 = *(const uint4*)(gB1);
        }

        const u16* Ab = As + par * 4096;
        const u16* Bb = Bs + par * 4096;
        short8 av[4], bv_[4];
#pragma unroll
        for (int k = 0; k < 4; k++) av[k] = *(const short8*)(Ab + aoff[k]);
#pragma unroll
        for (int k = 0; k < 4; k++) bv_[k] = *(const short8*)(Bb + boff[k]);
#pragma unroll
        for (int k = 0; k < 4; k++)
#pragma unroll
            for (int j = 0; j < 4; j++)
                acc[k][j] = __builtin_amdgcn_mfma_f32_16x16x32_bf16(av[k], bv_[j], acc[k][j], 0, 0, 0);

        if (i < 63) {                               // stage next tile into other buffer
            u16* Aw = As + (par ^ 1) * 4096;
            u16* Bw = Bs + (par ^ 1) * 4096;
            uint4 pa0 = make_uint4(pkbf(a00.x, a00.y), pkbf(a00.z, a00.w), pkbf(a01.x, a01.y), pkbf(a01.z, a01.w));
            uint4 pa1 = make_uint4(pkbf(a10.x, a10.y), pkbf(a10.z, a10.w), pkbf(a11.x, a11.y), pkbf(a11.z, a11.w));
            *(uint4*)(Aw + wo0) = pa0;
            *(uint4*)(Aw + wo1) = pa1;
            *(uint4*)(Bw + wo0) = b0;
            *(uint4*)(Bw + wo1) = b1;
        }
        __syncthreads();
    }

    // ---------------- fused epilogues ----------------
    if (bn < 20) {
        const bool isQ = (bn < 16);
        const float qsc = isQ ? 0.08838834764831845f * 1.4426950408889634f : 1.0f;
        const float* bias = isQ ? bq : bk;
        const int head = isQ ? bn : (bn - 16);
        u16* base = isQ ? qro : kro;
        const int nheads = isQ ? NH : NKV;

        float* ep = Ep + wave * 1280;           // 64 rows x 20 words (2-way on write = free)
        const int rowg = bm + wm + lane;        // this lane's s-row (read phase)
        const int s = rowg & 2047, bidx = rowg >> 11;
        const float* fcp0 = fc + s * 64;
        const float* fsp0 = fs + s * 64;

#pragma unroll
        for (int j = 0; j < 4; j++) {
            const float bcol = bias[head * 128 + wn + j * 16 + r];
#pragma unroll
            for (int i = 0; i < 4; i++)
#pragma unroll
                for (int g = 0; g < 4; g++)
                    ep[(i * 16 + q4 * 4 + g) * 20 + r] = acc[i][j][g] + bcol;
            float4 x0 = *(float4*)(ep + lane * 20 + 0);
            float4 x1 = *(float4*)(ep + lane * 20 + 4);
            float4 x2 = *(float4*)(ep + lane * 20 + 8);
            float4 x3 = *(float4*)(ep + lane * 20 + 12);
            const int d0 = wn + j * 16;
            const int ii0 = d0 >> 1;
            float4 ca = *(const float4*)(fcp0 + ii0);
            float4 cb = *(const float4*)(fcp0 + ii0 + 4);
            float4 sa = *(const float4*)(fsp0 + ii0);
            float4 sb = *(const float4*)(fsp0 + ii0 + 4);
            float o[16];
            o[0]  = (x0.x * ca.x - x0.y * sa.x) * qsc;  o[1]  = (x0.x * sa.x + x0.y * ca.x) * qsc;
            o[2]  = (x0.z * ca.y - x0.w * sa.y) * qsc;  o[3]  = (x0.z * sa.y + x0.w * ca.y) * qsc;
            o[4]  = (x1.x * ca.z - x1.y * sa.z) * qsc;  o[5]  = (x1.x * sa.z + x1.y * ca.z) * qsc;
            o[6]  = (x1.z * ca.w - x1.w * sa.w) * qsc;  o[7]  = (x1.z * sa.w + x1.w * ca.w) * qsc;
            o[8]  = (x2.x * cb.x - x2.y * sb.x) * qsc;  o[9]  = (x2.x * sb.x + x2.y * cb.x) * qsc;
            o[10] = (x2.z * cb.y - x2.w * sb.y) * qsc;  o[11] = (x2.z * sb.y + x2.w * cb.y) * qsc;
            o[12] = (x3.x * cb.z - x3.y * sb.z) * qsc;  o[13] = (x3.x * sb.z + x3.y * cb.z) * qsc;
            o[14] = (x3.z * cb.w - x3.w * sb.w) * qsc;  o[15] = (x3.z * sb.w + x3.w * cb.w) * qsc;
            unsigned w0 = (unsigned)f2bf(o[0])  | ((unsigned)f2bf(o[1])  << 16);
            unsigned w1 = (unsigned)f2bf(o[2])  | ((unsigned)f2bf(o[3])  << 16);
            unsigned w2 = (unsigned)f2bf(o[4])  | ((unsigned)f2bf(o[5])  << 16);
            unsigned w3 = (unsigned)f2bf(o[6])  | ((unsigned)f2bf(o[7])  << 16);
            unsigned w4 = (unsigned)f2bf(o[8])  | ((unsigned)f2bf(o[9])  << 16);
            unsigned w5 = (unsigned)f2bf(o[10]) | ((unsigned)f2bf(o[11]) << 16);
            unsigned w6 = (unsigned)f2bf(o[12]) | ((unsigned)f2bf(o[13]) << 16);
            unsigned w7 = (unsigned)f2bf(o[14]) | ((unsigned)f2bf(o[15]) << 16);
            u16* dst = base + (((size_t)(bidx * nheads + head) * SS + s) << 7) + d0;
            *(uint4*)dst = make_uint4(w0, w1, w2, w3);
            *(uint4*)(dst + 8) = make_uint4(w4, w5, w6, w7);
        }
    } else {
        // V path: convert + transpose to vtr[B][KV][D][S]
#pragma unroll
        for (int j = 0; j < 4; j++) {
            const int col = bn * 128 + wn + j * 16 + r - 2560;
            const int d = col & 127, kv = col >> 7;
            const float bb = bv[col];
#pragma unroll
            for (int i = 0; i < 4; i++) {
                const int row0 = bm + wm + i * 16 + q4 * 4;
                const int s0 = row0 & 2047, b = row0 >> 11;
                uint2 o;
                o.x = (unsigned)f2bf(acc[i][j][0] + bb) | ((unsigned)f2bf(acc[i][j][1] + bb) << 16);
                o.y = (unsigned)f2bf(acc[i][j][2] + bb) | ((unsigned)f2bf(acc[i][j][3] + bb) << 16);
                *(uint2*)(vtr + ((size_t)(b * NKV + kv) * DD + d) * SS + s0) = o;
            }
        }
    }
}

// ---------------- O-projection GEMM (pipelined K-loop, bf16 A): C = A*Bt^T + bias, fp32 out ---
__global__ __launch_bounds__(256) void k_gemm_bt(const u16* __restrict__ A,
                                                 const u16* __restrict__ Bt,
                                                 const float* __restrict__ bias,
                                                 float* __restrict__ C,
                                                 int M, int N, int K) {
    __shared__ char smem[32768];
    u16* As = (u16*)smem;
    u16* Bs = (u16*)(smem + 16384);

    const int tid = threadIdx.x;
    const int lane = tid & 63, wave = tid >> 6;
    const int bm = blockIdx.y * 128, bn = blockIdx.x * 128;

    const int srow = tid >> 2, spos = tid & 3;
    const int swz = (srow >> 1) & 3;
    const int c0 = (spos ^ swz) * 8;
    const u16* gA0 = A + (size_t)(bm + srow) * K + c0;
    const u16* gA1 = gA0 + (size_t)64 * K;
    const u16* gB0 = Bt + (size_t)(bn + srow) * K + c0;
    const u16* gB1 = gB0 + (size_t)64 * K;
    const int wo0 = srow * 32 + spos * 8;
    const int wo1 = wo0 + 64 * 32;

    const int r = lane & 15, q4 = lane >> 4;
    const int wm = (wave & 1) * 64, wn = (wave >> 1) * 64;

    int aoff[4], boff[4];
#pragma unroll
    for (int i = 0; i < 4; i++) {
        const int ar = wm + i * 16 + r;
        aoff[i] = ar * 32 + ((q4 ^ ((ar >> 1) & 3)) << 3);
        const int br = wn + i * 16 + r;
        boff[i] = br * 32 + ((q4 ^ ((br >> 1) & 3)) << 3);
    }

    f32x4 acc[4][4] = {};

    {
        uint4 a0 = *(const uint4*)(gA0), a1 = *(const uint4*)(gA1);
        uint4 b0 = *(const uint4*)(gB0), b1 = *(const uint4*)(gB1);
        *(uint4*)(As + wo0) = a0;
        *(uint4*)(As + wo1) = a1;
        *(uint4*)(Bs + wo0) = b0;
        *(uint4*)(Bs + wo1) = b1;
    }
    __syncthreads();

    const int iters = K / 32;
    for (int i = 0; i < iters; i++) {
        const int par = i & 1;
        uint4 a0, a1, b0, b1;
        if (i < iters - 1) {
            gA0 += 32; gA1 += 32; gB0 += 32; gB1 += 32;
            a0 = *(const uint4*)(gA0); a1 = *(const uint4*)(gA1);
            b0 = *(const uint4*)(gB0); b1 = *(const uint4*)(gB1);
        }

        const u16* Ab = As + par * 4096;
        const u16* Bb = Bs + par * 4096;
        short8 av[4], bv_[4];
#pragma unroll
        for (int k = 0; k < 4; k++) av[k] = *(const short8*)(Ab + aoff[k]);
#pragma unroll
        for (int k = 0; k < 4; k++) bv_[k] = *(const short8*)(Bb + boff[k]);
#pragma unroll
        for (int k = 0; k < 4; k++)
#pragma unroll
            for (int j = 0; j < 4; j++)
                acc[k][j] = __builtin_amdgcn_mfma_f32_16x16x32_bf16(av[k], bv_[j], acc[k][j], 0, 0, 0);

        if (i < iters - 1) {
            u16* Aw = As + (par ^ 1) * 4096;
            u16* Bw = Bs + (par ^ 1) * 4096;
            *(uint4*)(Aw + wo0) = a0;
            *(uint4*)(Aw + wo1) = a1;
            *(uint4*)(Bw + wo0) = b0;
            *(uint4*)(Bw + wo1) = b1;
        }
        __syncthreads();
    }

#pragma unroll
    for (int j = 0; j < 4; j++) {
        const int col = bn + wn + j * 16 + r;
        const float bb = bias[col];
#pragma unroll
        for (int i = 0; i < 4; i++) {
            const int row = bm + wm + i * 16 + q4 * 4;
#pragma unroll
            for (int g = 0; g < 4; g++)
                C[(size_t)(row + g) * N + col] = acc[i][j][g] + bb;
        }
    }
}

// ---------------- flash attention: no-max 2^s softmax, 32 q-rows/wave ----------------
__global__ __launch_bounds__(256) void k_attn(const u16* __restrict__ Q,   // [B*H][S][D] (scaled)
                                              const u16* __restrict__ K_,  // [B*KV][S][D]
                                              const u16* __restrict__ V_,  // [B*KV][D][S]
                                              u16* __restrict__ Ctx) {     // [B*S][H*D]
    __shared__ u16 Ks[32 * 128];       // 8 KB
    __shared__ u16 Vs[128 * 32];       // 8 KB
    __shared__ u16 Pb[4 * 32 * 40];    // 10 KB, 80B row stride

    const int tid = threadIdx.x;
    const int lane = tid & 63, wave = tid >> 6;
    const int bh = blockIdx.x;
    const int b = bh >> 4, h = bh & 15;
    const int kvh = (b << 2) | (h >> 2);
    const int qb = (gridDim.y - 1 - blockIdx.y) * 128;   // heavy-first
    const int qcol = lane & 15, q4 = lane >> 4;
    const int qw = qb + wave * 32;

    const u16* Qg = Q + ((size_t)bh * SS + qw + qcol) * DD;
    short8 qfr[2][4];
#pragma unroll
    for (int qi = 0; qi < 2; qi++)
#pragma unroll
        for (int c = 0; c < 4; c++)
            qfr[qi][c] = *(const short8*)(Qg + qi * 16 * DD + c * 32 + q4 * 8);

    const u16* Kg = K_ + (size_t)kvh * SS * DD;
    const u16* Vg = V_ + (size_t)kvh * DD * SS;

    const int krow = tid >> 4;
    const int kchunk = (tid & 15) ^ (krow & 7);
    const int vd = tid >> 2;
    const int vchunk = (tid & 3) ^ ((vd >> 1) & 3);

    f32x4 lacc[2] = {};
    f32x4 oacc[2][8] = {};

    const short8 ones = {0x3F80, 0x3F80, 0x3F80, 0x3F80, 0x3F80, 0x3F80, 0x3F80, 0x3F80};
    u16* pb = Pb + wave * 1280;
    unsigned* pb32 = (unsigned*)pb;

    for (int kb = 0; kb < qb + 128; kb += 32) {
        __builtin_amdgcn_global_load_lds(
            (const __attribute__((address_space(1))) void*)(uintptr_t)(Kg + (size_t)(kb + krow) * DD + kchunk * 8),
            (__attribute__((address_space(3))) void*)(uintptr_t)(Ks + wave * 512), 16, 0, 0);
        __builtin_amdgcn_global_load_lds(
            (const __attribute__((address_space(1))) void*)(uintptr_t)(Kg + (size_t)(kb + 16 + krow) * DD + kchunk * 8),
            (__attribute__((address_space(3))) void*)(uintptr_t)(Ks + 2048 + wave * 512), 16, 0, 0);
        __builtin_amdgcn_global_load_lds(
            (const __attribute__((address_space(1))) void*)(uintptr_t)(Vg + (size_t)vd * SS + kb + vchunk * 8),
            (__attribute__((address_space(3))) void*)(uintptr_t)(Vs + wave * 512), 16, 0, 0);
        __builtin_amdgcn_global_load_lds(
            (const __attribute__((address_space(1))) void*)(uintptr_t)(Vg + (size_t)(vd + 64) * SS + kb + vchunk * 8),
            (__attribute__((address_space(3))) void*)(uintptr_t)(Vs + 2048 + wave * 512), 16, 0, 0);
        __syncthreads();

        if (kb <= qw + 31) {                           // wave-uniform causal skip
            f32x4 sc[2][2] = {};
#pragma unroll
            for (int kt = 0; kt < 2; kt++) {
                const int kr = kt * 16 + qcol;
#pragma unroll
                for (int c = 0; c < 4; c++) {
                    short8 kf = *(const short8*)(Ks + kr * 128 + (((c * 4 + q4) ^ (kr & 7)) << 3));
                    sc[kt][0] = __builtin_amdgcn_mfma_f32_16x16x32_bf16(kf, qfr[0][c], sc[kt][0], 0, 0, 0);
                    sc[kt][1] = __builtin_amdgcn_mfma_f32_16x16x32_bf16(kf, qfr[1][c], sc[kt][1], 0, 0, 0);
                }
            }

            if (kb + 32 > qw) {                        // diagonal tiles only
#pragma unroll
                for (int kt = 0; kt < 2; kt++)
#pragma unroll
                    for (int qi = 0; qi < 2; qi++)
#pragma unroll
                        for (int g = 0; g < 4; g++) {
                            const int key = kb + kt * 16 + q4 * 4 + g;
                            if (key > qw + qi * 16 + qcol) sc[kt][qi][g] = -1e30f;
                        }
            }

            const unsigned sel = 0x07060302u;
#pragma unroll
            for (int qi = 0; qi < 2; qi++) {
                float p0 = EXP2(sc[0][qi][0]), p1 = EXP2(sc[0][qi][1]);
                float p2 = EXP2(sc[0][qi][2]), p3 = EXP2(sc[0][qi][3]);
                float p4 = EXP2(sc[1][qi][0]), p5 = EXP2(sc[1][qi][1]);
                float p6 = EXP2(sc[1][qi][2]), p7 = EXP2(sc[1][qi][3]);
                unsigned pk0 = __builtin_amdgcn_perm(__float_as_uint(p1), __float_as_uint(p0), sel);
                unsigned pk1 = __builtin_amdgcn_perm(__float_as_uint(p3), __float_as_uint(p2), sel);
                unsigned pk2 = __builtin_amdgcn_perm(__float_as_uint(p5), __float_as_uint(p4), sel);
                unsigned pk3 = __builtin_amdgcn_perm(__float_as_uint(p7), __float_as_uint(p6), sel);
                const int row = qi * 16 + qcol;
                *(uint2*)(pb32 + row * 20 + 2 * q4)     = make_uint2(pk0, pk1);
                *(uint2*)(pb32 + row * 20 + 8 + 2 * q4) = make_uint2(pk2, pk3);
            }

            short8 pf0 = *(const short8*)(pb + qcol * 40 + q4 * 8);
            short8 pf1 = *(const short8*)(pb + (16 + qcol) * 40 + q4 * 8);

            lacc[0] = __builtin_amdgcn_mfma_f32_16x16x32_bf16(ones, pf0, lacc[0], 0, 0, 0);
            lacc[1] = __builtin_amdgcn_mfma_f32_16x16x32_bf16(ones, pf1, lacc[1], 0, 0, 0);
#pragma unroll
            for (int dt = 0; dt < 8; dt++) {
                const int vr = dt * 16 + qcol;
                short8 vfr = *(const short8*)(Vs + vr * 32 + ((q4 ^ ((vr >> 1) & 3)) << 3));
                oacc[0][dt] = __builtin_amdgcn_mfma_f32_16x16x32_bf16(vfr, pf0, oacc[0][dt], 0, 0, 0);
                oacc[1][dt] = __builtin_amdgcn_mfma_f32_16x16x32_bf16(vfr, pf1, oacc[1][dt], 0, 0, 0);
            }
        }
        __syncthreads();
    }

#pragma unroll
    for (int qi = 0; qi < 2; qi++) {
        const float inv = 1.0f / lacc[qi][0];
        u16* outp = Ctx + ((size_t)b * SS + qw + qi * 16 + qcol) * (NH * DD) + h * DD;
#pragma unroll
        for (int dt = 0; dt < 8; dt++) {
            unsigned lo = (unsigned)f2bf(oacc[qi][dt][0] * inv) | ((unsigned)f2bf(oacc[qi][dt][1] * inv) << 16);
            unsigned hi = (unsigned)f2bf(oacc[qi][dt][2] * inv) | ((unsigned)f2bf(oacc[qi][dt][3] * inv) << 16);
            *(uint2*)(outp + dt * 16 + q4 * 4) = make_uint2(lo, hi);
        }
    }
}

extern "C" void kernel_launch(void* const* d_in, const int* in_sizes, int n_in,
                              void* d_out, int out_size, void* d_ws, size_t ws_size,
                              hipStream_t stream) {
    const float* query = (const float*)d_in[0];
    const float* key   = (const float*)d_in[1];
    const float* value = (const float*)d_in[2];
    const float* fc    = (const float*)d_in[4];
    const float* fs    = (const float*)d_in[5];
    const float* Wq    = (const float*)d_in[6];
    const float* bq    = (const float*)d_in[7];
    const float* Wk    = (const float*)d_in[8];
    const float* bk    = (const float*)d_in[9];
    const float* Wv    = (const float*)d_in[10];
    const float* bv    = (const float*)d_in[11];
    const float* Wo    = (const float*)d_in[12];
    const float* bo    = (const float*)d_in[13];
    float* out = (float*)d_out;

    char* w = (char*)d_ws;
    u16* Wt  = (u16*)(w);                    // 12 MB  [Wq|Wk|Wv]^T bf16 [3072][2048]
    u16* Wot = (u16*)(w + 12582912);         //  8 MB  Wo^T bf16 [2048][2048]
    u16* qro = (u16*)(w + 20971520);         // 16 MB  roped+scaled q bf16 [B][H][S][D]
    u16* kro = (u16*)(w + 37748736);         //  4 MB  roped k bf16 [B][KV][S][D]
    u16* vtr = (u16*)(w + 41943040);         //  4 MB  v bf16 [B][KV][D][S]
    u16* ctx = (u16*)(w + 46137344);         // 16 MB  ctx bf16 [4096][2048]  (end ~60 MB)

    k_prep<<<10240, 256, 0, stream>>>(Wq, Wk, Wv, Wo, Wt, Wot);
    k_gemm_qkv<<<dim3(24, 32), 256, 0, stream>>>(query, key, value, Wt, bq, bk, bv,
                                                 fc, fs, qro, kro, vtr);
    k_attn<<<dim3(32, 16), 256, 0, stream>>>(qro, kro, vtr, ctx);
    k_gemm_bt<<<dim3(16, 32), 256, 0, stream>>>(ctx, Wot, bo, out, 4096, 2048, 2048);
}

// Round 6
// 397.570 us; speedup vs baseline: 1.1170x; 1.1170x over previous
//
#include <hip/hip_runtime.h>
#include <stdint.h>

// Problem constants
#define BB 2
#define SS 2048
#define HID 2048
#define NH 16
#define DD 128
#define NKV 4

typedef unsigned short u16;
typedef __attribute__((ext_vector_type(8))) short short8;   // 8 x bf16 (4 VGPRs) MFMA A/B frag
typedef __attribute__((ext_vector_type(4))) float f32x4;    // MFMA C/D frag

#if __has_builtin(__builtin_amdgcn_exp2f)
#define EXP2(x) __builtin_amdgcn_exp2f(x)
#else
#define EXP2(x) exp2f(x)
#endif

__device__ __forceinline__ u16 f2bf(float x) {
    union { float f; unsigned u; } v; v.f = x;
    unsigned u = v.u;
    return (u16)((u + 0x7FFFu + ((u >> 16) & 1u)) >> 16);   // RNE
}

// async global->LDS, 16B per lane. lds ptr must be wave-uniform (HW adds lane*16).
__device__ __forceinline__ void async_lds16(const void* g, void* l) {
    __builtin_amdgcn_global_load_lds(
        (const __attribute__((address_space(1))) void*)(uintptr_t)g,
        (__attribute__((address_space(3))) void*)(uintptr_t)l,
        16, 0, 0);
}

// ---------------- prep: fp32->bf16 converts (q,k,v) + all weight transposes, one launch ------
__global__ __launch_bounds__(256) void k_prep(const float* __restrict__ query,
                                              const float* __restrict__ key,
                                              const float* __restrict__ value,
                                              const float* __restrict__ Wq,
                                              const float* __restrict__ Wk,
                                              const float* __restrict__ Wv,
                                              const float* __restrict__ Wo,
                                              u16* __restrict__ qbf,
                                              u16* __restrict__ kbf,
                                              u16* __restrict__ vbf,
                                              u16* __restrict__ Wt,
                                              u16* __restrict__ Wot) {
    __shared__ float tile[32][33];
    int x = blockIdx.x;
    if (x < 24576) {
        const float* in; u16* out;
        if (x < 8192)       { in = query; out = qbf; }
        else if (x < 16384) { in = key;   out = kbf; x -= 8192; }
        else                { in = value; out = vbf; x -= 16384; }
        const int i = x * 256 + threadIdx.x;
        float4 v = ((const float4*)in)[i];
        uint2 o;
        o.x = (unsigned)f2bf(v.x) | ((unsigned)f2bf(v.y) << 16);
        o.y = (unsigned)f2bf(v.z) | ((unsigned)f2bf(v.w) << 16);
        ((uint2*)out)[i] = o;
        return;
    }
    const int v_ = x - 24576;            // 0..10239
    const int ty = v_ / 160;             // k-tile 0..63
    const int xt = v_ - ty * 160;        // n-tile 0..159
    const float* src; u16* dst; int N, n0;
    if (xt < 64)      { src = Wq; dst = Wt;                          N = 2048; n0 = xt * 32; }
    else if (xt < 80) { src = Wk; dst = Wt + (size_t)2048 * 2048;    N = 512;  n0 = (xt - 64) * 32; }
    else if (xt < 96) { src = Wv; dst = Wt + (size_t)2560 * 2048;    N = 512;  n0 = (xt - 80) * 32; }
    else              { src = Wo; dst = Wot;                         N = 2048; n0 = (xt - 96) * 32; }
    const int k0 = ty * 32;
    const int c = threadIdx.x & 31, r = threadIdx.x >> 5;
#pragma unroll
    for (int i = 0; i < 32; i += 8)
        tile[r + i][c] = src[(size_t)(k0 + r + i) * N + n0 + c];
    __syncthreads();
#pragma unroll
    for (int i = 0; i < 32; i += 8)
        dst[(size_t)(n0 + r + i) * 2048 + k0 + c] = f2bf(tile[c][r + i]);
}

// ---------------- fused QKV projection GEMM, BK=64 ----------------
// grid (24, 32) = 768 blocks (3/CU, all resident). bn<16: Q-proj (RoPE+scale -> qro);
// bn 16..19: K-proj (RoPE -> kro); bn 20..23: V-proj (-> vtr transposed).
// BK=64 halves the barrier/vmcnt-drain count per MFMA vs BK=32 (32 iters, 32 MFMA/iter).
// LDS 32 KB single-buffered; 8-chunk rows with full ar&7 XOR swizzle (2-way ds_read = free).
__global__ __launch_bounds__(256) void k_gemm_qkv(const u16* __restrict__ qbf,
                                                  const u16* __restrict__ kbf,
                                                  const u16* __restrict__ vbf,
                                                  const u16* __restrict__ Wt,   // [3072][2048] bf16
                                                  const float* __restrict__ bq,
                                                  const float* __restrict__ bk,
                                                  const float* __restrict__ bv,
                                                  const float* __restrict__ fc,
                                                  const float* __restrict__ fs,
                                                  u16* __restrict__ qro,
                                                  u16* __restrict__ kro,
                                                  u16* __restrict__ vtr) {
    __shared__ char smem[32768];
    u16* As = (u16*)smem;                  // 128x64 bf16 (16 KB)
    u16* Bs = (u16*)(smem + 16384);        // 128x64 bf16 (16 KB)
    float* Ep = (float*)smem;              // epilogue scratch (20 KB), aliased post-loop

    const int tid = threadIdx.x;
    const int lane = tid & 63, wave = tid >> 6;
    const int bn = blockIdx.x;
    const int bm = blockIdx.y * 128;
    const u16* A = (bn < 16) ? qbf : (bn < 20) ? kbf : vbf;

    // staging map: per call, wave w covers rows base+w*8+(lane>>3), chunk lane&7 (swizzled src)
    const int srow = wave * 8 + (lane >> 3);
    const int c0 = ((lane & 7) ^ (lane >> 3)) * 8;
    const u16* gA = A  + (size_t)(bm + srow) * 2048 + c0;
    const u16* gB = Wt + (size_t)(bn * 128 + srow) * 2048 + c0;

    const int r = lane & 15, q4 = lane >> 4;
    const int wm = (wave & 1) * 64, wn = (wave >> 1) * 64;

    int aoff[4][2], boff[4][2];
#pragma unroll
    for (int i = 0; i < 4; i++) {
        const int ar = wm + i * 16 + r;
        const int pa = q4 ^ (ar & 7);
        aoff[i][0] = ar * 64 + pa * 8;
        aoff[i][1] = ar * 64 + (pa ^ 4) * 8;
        const int br = wn + i * 16 + r;
        const int pb = q4 ^ (br & 7);
        boff[i][0] = br * 64 + pb * 8;
        boff[i][1] = br * 64 + (pb ^ 4) * 8;
    }

    f32x4 acc[4][4] = {};

    for (int kb = 0; kb < 2048; kb += 64) {
        async_lds16(gA,                       As + wave * 512);
        async_lds16(gA + (size_t)32 * 2048,   As + 2048 + wave * 512);
        async_lds16(gA + (size_t)64 * 2048,   As + 4096 + wave * 512);
        async_lds16(gA + (size_t)96 * 2048,   As + 6144 + wave * 512);
        async_lds16(gB,                       Bs + wave * 512);
        async_lds16(gB + (size_t)32 * 2048,   Bs + 2048 + wave * 512);
        async_lds16(gB + (size_t)64 * 2048,   Bs + 4096 + wave * 512);
        async_lds16(gB + (size_t)96 * 2048,   Bs + 6144 + wave * 512);
        gA += 64; gB += 64;
        __syncthreads();

#pragma unroll
        for (int kk = 0; kk < 2; kk++) {
            short8 av[4], bv_[4];
#pragma unroll
            for (int i = 0; i < 4; i++) av[i] = *(const short8*)(As + aoff[i][kk]);
#pragma unroll
            for (int j = 0; j < 4; j++) bv_[j] = *(const short8*)(Bs + boff[j][kk]);
#pragma unroll
            for (int i = 0; i < 4; i++)
#pragma unroll
                for (int j = 0; j < 4; j++)
                    acc[i][j] = __builtin_amdgcn_mfma_f32_16x16x32_bf16(av[i], bv_[j], acc[i][j], 0, 0, 0);
        }
        __syncthreads();
    }

    // ---------------- fused epilogues (Ep aliases As/Bs; in-wave DS ordering, no barrier) ------
    if (bn < 20) {
        const bool isQ = (bn < 16);
        const float qsc = isQ ? 0.08838834764831845f * 1.4426950408889634f : 1.0f;
        const float* bias = isQ ? bq : bk;
        const int head = isQ ? bn : (bn - 16);
        u16* base = isQ ? qro : kro;
        const int nheads = isQ ? NH : NKV;

        float* ep = Ep + wave * 1280;           // 64 rows x 20 words (2-way on write = free)
        const int rowg = bm + wm + lane;        // this lane's s-row (read phase)
        const int s = rowg & 2047, bidx = rowg >> 11;
        const float* fcp0 = fc + s * 64;
        const float* fsp0 = fs + s * 64;

#pragma unroll
        for (int j = 0; j < 4; j++) {
            const float bcol = bias[head * 128 + wn + j * 16 + r];
#pragma unroll
            for (int i = 0; i < 4; i++)
#pragma unroll
                for (int g = 0; g < 4; g++)
                    ep[(i * 16 + q4 * 4 + g) * 20 + r] = acc[i][j][g] + bcol;
            float4 x0 = *(float4*)(ep + lane * 20 + 0);
            float4 x1 = *(float4*)(ep + lane * 20 + 4);
            float4 x2 = *(float4*)(ep + lane * 20 + 8);
            float4 x3 = *(float4*)(ep + lane * 20 + 12);
            const int d0 = wn + j * 16;
            const int ii0 = d0 >> 1;
            float4 ca = *(const float4*)(fcp0 + ii0);
            float4 cb = *(const float4*)(fcp0 + ii0 + 4);
            float4 sa = *(const float4*)(fsp0 + ii0);
            float4 sb = *(const float4*)(fsp0 + ii0 + 4);
            float o[16];
            o[0]  = (x0.x * ca.x - x0.y * sa.x) * qsc;  o[1]  = (x0.x * sa.x + x0.y * ca.x) * qsc;
            o[2]  = (x0.z * ca.y - x0.w * sa.y) * qsc;  o[3]  = (x0.z * sa.y + x0.w * ca.y) * qsc;
            o[4]  = (x1.x * ca.z - x1.y * sa.z) * qsc;  o[5]  = (x1.x * sa.z + x1.y * ca.z) * qsc;
            o[6]  = (x1.z * ca.w - x1.w * sa.w) * qsc;  o[7]  = (x1.z * sa.w + x1.w * ca.w) * qsc;
            o[8]  = (x2.x * cb.x - x2.y * sb.x) * qsc;  o[9]  = (x2.x * sb.x + x2.y * cb.x) * qsc;
            o[10] = (x2.z * cb.y - x2.w * sb.y) * qsc;  o[11] = (x2.z * sb.y + x2.w * cb.y) * qsc;
            o[12] = (x3.x * cb.z - x3.y * sb.z) * qsc;  o[13] = (x3.x * sb.z + x3.y * cb.z) * qsc;
            o[14] = (x3.z * cb.w - x3.w * sb.w) * qsc;  o[15] = (x3.z * sb.w + x3.w * cb.w) * qsc;
            unsigned w0 = (unsigned)f2bf(o[0])  | ((unsigned)f2bf(o[1])  << 16);
            unsigned w1 = (unsigned)f2bf(o[2])  | ((unsigned)f2bf(o[3])  << 16);
            unsigned w2 = (unsigned)f2bf(o[4])  | ((unsigned)f2bf(o[5])  << 16);
            unsigned w3 = (unsigned)f2bf(o[6])  | ((unsigned)f2bf(o[7])  << 16);
            unsigned w4 = (unsigned)f2bf(o[8])  | ((unsigned)f2bf(o[9])  << 16);
            unsigned w5 = (unsigned)f2bf(o[10]) | ((unsigned)f2bf(o[11]) << 16);
            unsigned w6 = (unsigned)f2bf(o[12]) | ((unsigned)f2bf(o[13]) << 16);
            unsigned w7 = (unsigned)f2bf(o[14]) | ((unsigned)f2bf(o[15]) << 16);
            u16* dst = base + (((size_t)(bidx * nheads + head) * SS + s) << 7) + d0;
            *(uint4*)dst = make_uint4(w0, w1, w2, w3);
            *(uint4*)(dst + 8) = make_uint4(w4, w5, w6, w7);
        }
    } else {
        // V path: convert + transpose to vtr[B][KV][D][S]
#pragma unroll
        for (int j = 0; j < 4; j++) {
            const int col = bn * 128 + wn + j * 16 + r - 2560;
            const int d = col & 127, kv = col >> 7;
            const float bb = bv[col];
#pragma unroll
            for (int i = 0; i < 4; i++) {
                const int row0 = bm + wm + i * 16 + q4 * 4;
                const int s0 = row0 & 2047, b = row0 >> 11;
                uint2 o;
                o.x = (unsigned)f2bf(acc[i][j][0] + bb) | ((unsigned)f2bf(acc[i][j][1] + bb) << 16);
                o.y = (unsigned)f2bf(acc[i][j][2] + bb) | ((unsigned)f2bf(acc[i][j][3] + bb) << 16);
                *(uint2*)(vtr + ((size_t)(b * NKV + kv) * DD + d) * SS + s0) = o;
            }
        }
    }
}

// ---------------- O-projection GEMM, BK=64: C[M][N] = A[M][K]*Bt[N][K]^T + bias, fp32 out -----
__global__ __launch_bounds__(256) void k_gemm_bt(const u16* __restrict__ A,
                                                 const u16* __restrict__ Bt,
                                                 const float* __restrict__ bias,
                                                 float* __restrict__ C,
                                                 int M, int N, int K) {
    __shared__ char smem[32768];
    u16* As = (u16*)smem;
    u16* Bs = (u16*)(smem + 16384);

    const int tid = threadIdx.x;
    const int lane = tid & 63, wave = tid >> 6;
    const int bm = blockIdx.y * 128, bn = blockIdx.x * 128;

    const int srow = wave * 8 + (lane >> 3);
    const int c0 = ((lane & 7) ^ (lane >> 3)) * 8;
    const u16* gA = A  + (size_t)(bm + srow) * K + c0;
    const u16* gB = Bt + (size_t)(bn + srow) * K + c0;

    const int r = lane & 15, q4 = lane >> 4;
    const int wm = (wave & 1) * 64, wn = (wave >> 1) * 64;

    int aoff[4][2], boff[4][2];
#pragma unroll
    for (int i = 0; i < 4; i++) {
        const int ar = wm + i * 16 + r;
        const int pa = q4 ^ (ar & 7);
        aoff[i][0] = ar * 64 + pa * 8;
        aoff[i][1] = ar * 64 + (pa ^ 4) * 8;
        const int br = wn + i * 16 + r;
        const int pb = q4 ^ (br & 7);
        boff[i][0] = br * 64 + pb * 8;
        boff[i][1] = br * 64 + (pb ^ 4) * 8;
    }

    f32x4 acc[4][4] = {};

    for (int kb = 0; kb < K; kb += 64) {
        async_lds16(gA,                    As + wave * 512);
        async_lds16(gA + (size_t)32 * K,   As + 2048 + wave * 512);
        async_lds16(gA + (size_t)64 * K,   As + 4096 + wave * 512);
        async_lds16(gA + (size_t)96 * K,   As + 6144 + wave * 512);
        async_lds16(gB,                    Bs + wave * 512);
        async_lds16(gB + (size_t)32 * K,   Bs + 2048 + wave * 512);
        async_lds16(gB + (size_t)64 * K,   Bs + 4096 + wave * 512);
        async_lds16(gB + (size_t)96 * K,   Bs + 6144 + wave * 512);
        gA += 64; gB += 64;
        __syncthreads();

#pragma unroll
        for (int kk = 0; kk < 2; kk++) {
            short8 av[4], bv_[4];
#pragma unroll
            for (int i = 0; i < 4; i++) av[i] = *(const short8*)(As + aoff[i][kk]);
#pragma unroll
            for (int j = 0; j < 4; j++) bv_[j] = *(const short8*)(Bs + boff[j][kk]);
#pragma unroll
            for (int i = 0; i < 4; i++)
#pragma unroll
                for (int j = 0; j < 4; j++)
                    acc[i][j] = __builtin_amdgcn_mfma_f32_16x16x32_bf16(av[i], bv_[j], acc[i][j], 0, 0, 0);
        }
        __syncthreads();
    }

#pragma unroll
    for (int j = 0; j < 4; j++) {
        const int col = bn + wn + j * 16 + r;
        const float bb = bias[col];
#pragma unroll
        for (int i = 0; i < 4; i++) {
            const int row = bm + wm + i * 16 + q4 * 4;
#pragma unroll
            for (int g = 0; g < 4; g++)
                C[(size_t)(row + g) * N + col] = acc[i][j][g] + bb;
        }
    }
}

// ---------------- flash attention: no-max 2^s softmax, 32 q-rows/wave ----------------
__global__ __launch_bounds__(256) void k_attn(const u16* __restrict__ Q,   // [B*H][S][D] (scaled)
                                              const u16* __restrict__ K_,  // [B*KV][S][D]
                                              const u16* __restrict__ V_,  // [B*KV][D][S]
                                              u16* __restrict__ Ctx) {     // [B*S][H*D]
    __shared__ u16 Ks[32 * 128];       // 8 KB
    __shared__ u16 Vs[128 * 32];       // 8 KB
    __shared__ u16 Pb[4 * 32 * 40];    // 10 KB, 80B row stride

    const int tid = threadIdx.x;
    const int lane = tid & 63, wave = tid >> 6;
    const int bh = blockIdx.x;
    const int b = bh >> 4, h = bh & 15;
    const int kvh = (b << 2) | (h >> 2);
    const int qb = (gridDim.y - 1 - blockIdx.y) * 128;   // heavy-first
    const int qcol = lane & 15, q4 = lane >> 4;
    const int qw = qb + wave * 32;

    const u16* Qg = Q + ((size_t)bh * SS + qw + qcol) * DD;
    short8 qfr[2][4];
#pragma unroll
    for (int qi = 0; qi < 2; qi++)
#pragma unroll
        for (int c = 0; c < 4; c++)
            qfr[qi][c] = *(const short8*)(Qg + qi * 16 * DD + c * 32 + q4 * 8);

    const u16* Kg = K_ + (size_t)kvh * SS * DD;
    const u16* Vg = V_ + (size_t)kvh * DD * SS;

    const int krow = tid >> 4;
    const int kchunk = (tid & 15) ^ (krow & 7);
    const int vd = tid >> 2;
    const int vchunk = (tid & 3) ^ ((vd >> 1) & 3);

    f32x4 lacc[2] = {};
    f32x4 oacc[2][8] = {};

    const short8 ones = {0x3F80, 0x3F80, 0x3F80, 0x3F80, 0x3F80, 0x3F80, 0x3F80, 0x3F80};
    u16* pb = Pb + wave * 1280;
    unsigned* pb32 = (unsigned*)pb;

    for (int kb = 0; kb < qb + 128; kb += 32) {
        async_lds16(Kg + (size_t)(kb + krow) * DD + kchunk * 8,       Ks + wave * 512);
        async_lds16(Kg + (size_t)(kb + 16 + krow) * DD + kchunk * 8,  Ks + 2048 + wave * 512);
        async_lds16(Vg + (size_t)vd * SS + kb + vchunk * 8,           Vs + wave * 512);
        async_lds16(Vg + (size_t)(vd + 64) * SS + kb + vchunk * 8,    Vs + 2048 + wave * 512);
        __syncthreads();

        if (kb <= qw + 31) {                           // wave-uniform causal skip
            f32x4 sc[2][2] = {};
#pragma unroll
            for (int kt = 0; kt < 2; kt++) {
                const int kr = kt * 16 + qcol;
#pragma unroll
                for (int c = 0; c < 4; c++) {
                    short8 kf = *(const short8*)(Ks + kr * 128 + (((c * 4 + q4) ^ (kr & 7)) << 3));
                    sc[kt][0] = __builtin_amdgcn_mfma_f32_16x16x32_bf16(kf, qfr[0][c], sc[kt][0], 0, 0, 0);
                    sc[kt][1] = __builtin_amdgcn_mfma_f32_16x16x32_bf16(kf, qfr[1][c], sc[kt][1], 0, 0, 0);
                }
            }

            if (kb + 32 > qw) {                        // diagonal tiles only
#pragma unroll
                for (int kt = 0; kt < 2; kt++)
#pragma unroll
                    for (int qi = 0; qi < 2; qi++)
#pragma unroll
                        for (int g = 0; g < 4; g++) {
                            const int key = kb + kt * 16 + q4 * 4 + g;
                            if (key > qw + qi * 16 + qcol) sc[kt][qi][g] = -1e30f;
                        }
            }

            const unsigned sel = 0x07060302u;
#pragma unroll
            for (int qi = 0; qi < 2; qi++) {
                float p0 = EXP2(sc[0][qi][0]), p1 = EXP2(sc[0][qi][1]);
                float p2 = EXP2(sc[0][qi][2]), p3 = EXP2(sc[0][qi][3]);
                float p4 = EXP2(sc[1][qi][0]), p5 = EXP2(sc[1][qi][1]);
                float p6 = EXP2(sc[1][qi][2]), p7 = EXP2(sc[1][qi][3]);
                unsigned pk0 = __builtin_amdgcn_perm(__float_as_uint(p1), __float_as_uint(p0), sel);
                unsigned pk1 = __builtin_amdgcn_perm(__float_as_uint(p3), __float_as_uint(p2), sel);
                unsigned pk2 = __builtin_amdgcn_perm(__float_as_uint(p5), __float_as_uint(p4), sel);
                unsigned pk3 = __builtin_amdgcn_perm(__float_as_uint(p7), __float_as_uint(p6), sel);
                const int row = qi * 16 + qcol;
                *(uint2*)(pb32 + row * 20 + 2 * q4)     = make_uint2(pk0, pk1);
                *(uint2*)(pb32 + row * 20 + 8 + 2 * q4) = make_uint2(pk2, pk3);
            }

            short8 pf0 = *(const short8*)(pb + qcol * 40 + q4 * 8);
            short8 pf1 = *(const short8*)(pb + (16 + qcol) * 40 + q4 * 8);

            lacc[0] = __builtin_amdgcn_mfma_f32_16x16x32_bf16(ones, pf0, lacc[0], 0, 0, 0);
            lacc[1] = __builtin_amdgcn_mfma_f32_16x16x32_bf16(ones, pf1, lacc[1], 0, 0, 0);
#pragma unroll
            for (int dt = 0; dt < 8; dt++) {
                const int vr = dt * 16 + qcol;
                short8 vfr = *(const short8*)(Vs + vr * 32 + ((q4 ^ ((vr >> 1) & 3)) << 3));
                oacc[0][dt] = __builtin_amdgcn_mfma_f32_16x16x32_bf16(vfr, pf0, oacc[0][dt], 0, 0, 0);
                oacc[1][dt] = __builtin_amdgcn_mfma_f32_16x16x32_bf16(vfr, pf1, oacc[1][dt], 0, 0, 0);
            }
        }
        __syncthreads();
    }

#pragma unroll
    for (int qi = 0; qi < 2; qi++) {
        const float inv = 1.0f / lacc[qi][0];
        u16* outp = Ctx + ((size_t)b * SS + qw + qi * 16 + qcol) * (NH * DD) + h * DD;
#pragma unroll
        for (int dt = 0; dt < 8; dt++) {
            unsigned lo = (unsigned)f2bf(oacc[qi][dt][0] * inv) | ((unsigned)f2bf(oacc[qi][dt][1] * inv) << 16);
            unsigned hi = (unsigned)f2bf(oacc[qi][dt][2] * inv) | ((unsigned)f2bf(oacc[qi][dt][3] * inv) << 16);
            *(uint2*)(outp + dt * 16 + q4 * 4) = make_uint2(lo, hi);
        }
    }
}

extern "C" void kernel_launch(void* const* d_in, const int* in_sizes, int n_in,
                              void* d_out, int out_size, void* d_ws, size_t ws_size,
                              hipStream_t stream) {
    const float* query = (const float*)d_in[0];
    const float* key   = (const float*)d_in[1];
    const float* value = (const float*)d_in[2];
    const float* fc    = (const float*)d_in[4];
    const float* fs    = (const float*)d_in[5];
    const float* Wq    = (const float*)d_in[6];
    const float* bq    = (const float*)d_in[7];
    const float* Wk    = (const float*)d_in[8];
    const float* bk    = (const float*)d_in[9];
    const float* Wv    = (const float*)d_in[10];
    const float* bv    = (const float*)d_in[11];
    const float* Wo    = (const float*)d_in[12];
    const float* bo    = (const float*)d_in[13];
    float* out = (float*)d_out;

    char* w = (char*)d_ws;
    u16* qbf = (u16*)(w);                    // 16 MB  bf16 query [4096][2048]
    u16* kbf = (u16*)(w + 16777216);         // 16 MB
    u16* vbf = (u16*)(w + 33554432);         // 16 MB
    u16* Wt  = (u16*)(w + 50331648);         // 12 MB  [Wq|Wk|Wv]^T bf16 [3072][2048]
    u16* Wot = (u16*)(w + 62914560);         //  8 MB  Wo^T bf16 [2048][2048]
    u16* qro = (u16*)(w + 71303168);         // 16 MB  roped+scaled q bf16 [B][H][S][D]
    u16* kro = (u16*)(w + 88080384);         //  4 MB  roped k bf16 [B][KV][S][D]
    u16* vtr = (u16*)(w + 92274688);         //  4 MB  v bf16 [B][KV][D][S]
    u16* ctx = (u16*)(w + 96468992);         // 16 MB  ctx bf16 [4096][2048]  (end 108 MB)

    k_prep<<<34816, 256, 0, stream>>>(query, key, value, Wq, Wk, Wv, Wo,
                                      qbf, kbf, vbf, Wt, Wot);
    k_gemm_qkv<<<dim3(24, 32), 256, 0, stream>>>(qbf, kbf, vbf, Wt, bq, bk, bv,
                                                 fc, fs, qro, kro, vtr);
    k_attn<<<dim3(32, 16), 256, 0, stream>>>(qro, kro, vtr, ctx);
    k_gemm_bt<<<dim3(16, 32), 256, 0, stream>>>(ctx, Wot, bo, out, 4096, 2048, 2048);
}